// Round 2
// baseline (3787.341 us; speedup 1.0000x reference)
//
#include <hip/hip_runtime.h>

#define BATCH 16
#define NPTS 16384
#define MCENT 1024
#define NSAMPLE 32
#define PPT 16   // points per thread in FPS

// ---- Morton code: 10 bits, (x:4, y:3, z:3), interleaved x y z x y z x y z x
__device__ __forceinline__ unsigned morton10(float x, float y, float z) {
    int qx = (int)(x * 16.0f); qx = qx < 0 ? 0 : (qx > 15 ? 15 : qx);
    int qy = (int)(y * 8.0f);  qy = qy < 0 ? 0 : (qy > 7 ? 7 : qy);
    int qz = (int)(z * 8.0f);  qz = qz < 0 ? 0 : (qz > 7 ? 7 : qz);
    unsigned c = 0;
    c |= (unsigned)(qx & 1) | ((unsigned)(qy & 1) << 1) | ((unsigned)(qz & 1) << 2);
    c |= (((unsigned)(qx >> 1) & 1) << 3) | (((unsigned)(qy >> 1) & 1) << 4) | (((unsigned)(qz >> 1) & 1) << 5);
    c |= (((unsigned)(qx >> 2) & 1) << 6) | (((unsigned)(qy >> 2) & 1) << 7) | (((unsigned)(qz >> 2) & 1) << 8);
    c |= (((unsigned)(qx >> 3) & 1) << 9);
    return c;
}

// ---------------- setup: Morton counting-sort per batch ----------------
// Non-stable (atomic order) is OK: all downstream logic tie-breaks on
// original index, so outputs are order-invariant and deterministic.
__global__ __launch_bounds__(1024) void sort_kernel(const float* __restrict__ xyz,
                                                    float4* __restrict__ sorted) {
    const int b = blockIdx.x;
    const int tid = threadIdx.x;
    const int lane = tid & 63;
    const int wid = tid >> 6;
    const float* xb = xyz + (size_t)b * NPTS * 3;
    float4* sb = sorted + (size_t)b * NPTS;

    __shared__ unsigned hist[1024];
    __shared__ unsigned wsum[16];
    hist[tid] = 0;
    __syncthreads();

    float mx[16], my[16], mz[16];
    unsigned mc[16];
#pragma unroll
    for (int j = 0; j < 16; ++j) {
        int p = j * 1024 + tid;
        mx[j] = xb[p * 3 + 0];
        my[j] = xb[p * 3 + 1];
        mz[j] = xb[p * 3 + 2];
        mc[j] = morton10(mx[j], my[j], mz[j]);
        atomicAdd(&hist[mc[j]], 1u);
    }
    __syncthreads();

    unsigned orig = hist[tid];
    unsigned v = orig;
#pragma unroll
    for (int off = 1; off < 64; off <<= 1) {
        unsigned n = __shfl_up(v, off);
        if (lane >= off) v += n;
    }
    if (lane == 63) wsum[wid] = v;
    __syncthreads();
    if (wid == 0 && lane < 16) {
        unsigned s = wsum[lane];
#pragma unroll
        for (int off = 1; off < 16; off <<= 1) {
            unsigned n = __shfl_up(s, off);
            if (lane >= off) s += n;
        }
        wsum[lane] = s;
    }
    __syncthreads();
    unsigned base = v - orig + (wid > 0 ? wsum[wid - 1] : 0u);
    __syncthreads();          // everyone done reading wsum/hist state
    hist[tid] = base;         // reuse as scatter cursor
    __syncthreads();

#pragma unroll
    for (int j = 0; j < 16; ++j) {
        int p = j * 1024 + tid;
        unsigned pos = atomicAdd(&hist[mc[j]], 1u);
        sb[pos] = make_float4(mx[j], my[j], mz[j], __int_as_float(p));
    }
}

// ---------------- FPS with bbox pruning ----------------
__global__ __launch_bounds__(1024) void fps_kernel(const float* __restrict__ xyz,
                                                   const float4* __restrict__ sorted,
                                                   float* __restrict__ cent_out) {
#pragma clang fp contract(off)
    const int b = blockIdx.x;
    const int tid = threadIdx.x;
    const int lane = tid & 63;
    const int wid = tid >> 6;
    const float4* sb = sorted + (size_t)b * NPTS;
    const float* xb = xyz + (size_t)b * NPTS * 3;
    float* cb = cent_out + (size_t)b * MCENT * 3;

    float px[PPT], py[PPT], pz[PPT], md[PPT];
    int pid[PPT];
    float blx = 1e30f, bly = 1e30f, blz = 1e30f;
    float bhx = -1e30f, bhy = -1e30f, bhz = -1e30f;
#pragma unroll
    for (int j = 0; j < PPT; ++j) {
        float4 v = sb[tid * PPT + j];
        px[j] = v.x; py[j] = v.y; pz[j] = v.z;
        pid[j] = __float_as_int(v.w);
        md[j] = 1e10f;
        blx = fminf(blx, v.x); bhx = fmaxf(bhx, v.x);
        bly = fminf(bly, v.y); bhy = fmaxf(bhy, v.y);
        blz = fminf(blz, v.z); bhz = fmaxf(bhz, v.z);
    }

    __shared__ float redv[2][16], redx[2][16], redy[2][16], redz[2][16];
    __shared__ int redi[2][16];

    // first centroid = original point 0 (broadcast load, once)
    float cx = xb[0], cy = xb[1], cz = xb[2];

    // per-thread cached local argmax, per-wave cached reduced argmax
    float bv = -1.0f; int bi = 0x7fffffff;
    float bxc = 0.f, byc = 0.f, bzc = 0.f;
    float wv = -1.0f; int wi = 0x7fffffff;
    float wx = 0.f, wy = 0.f, wz = 0.f;

    for (int m = 0; m < MCENT; ++m) {
        if (tid == 0) {
            cb[m * 3 + 0] = cx;
            cb[m * 3 + 1] = cy;
            cb[m * 3 + 2] = cz;
        }
        if (m == MCENT - 1) break;

        // lower bound of squared distance from centroid to this thread's bbox
        float tx = fmaxf(fmaxf(blx - cx, cx - bhx), 0.0f);
        float ty = fmaxf(fmaxf(bly - cy, cy - bhy), 0.0f);
        float tz = fmaxf(fmaxf(blz - cz, cz - bhz), 0.0f);
        float lb = tx * tx + ty * ty + tz * tz;
        bool active = (m == 0) || (lb * 0.999f < bv);

        if (active) {
            bv = -1.0f; bi = 0x7fffffff;
#pragma unroll
            for (int j = 0; j < PPT; ++j) {
                float dx = px[j] - cx;
                float dy = py[j] - cy;
                float dz = pz[j] - cz;
                float d = dx * dx + dy * dy;
                d = d + dz * dz;
                float nm = fminf(md[j], d);
                md[j] = nm;
                if (nm > bv || (nm == bv && pid[j] < bi)) {
                    bv = nm; bi = pid[j];
                    bxc = px[j]; byc = py[j]; bzc = pz[j];
                }
            }
        }

        unsigned long long act = __ballot(active);
        if (act != 0ull) {
            float v = bv; int i = bi;
            float x = bxc, y = byc, z = bzc;
#pragma unroll
            for (int off = 32; off >= 1; off >>= 1) {
                float ov = __shfl_xor(v, off);
                int   oi = __shfl_xor(i, off);
                float ox = __shfl_xor(x, off);
                float oy = __shfl_xor(y, off);
                float oz = __shfl_xor(z, off);
                if (ov > v || (ov == v && oi < i)) { v = ov; i = oi; x = ox; y = oy; z = oz; }
            }
            wv = v; wi = i; wx = x; wy = y; wz = z;
        }
        const int pb = m & 1;
        if (lane == 0) {
            redv[pb][wid] = wv; redi[pb][wid] = wi;
            redx[pb][wid] = wx; redy[pb][wid] = wy; redz[pb][wid] = wz;
        }
        __syncthreads();

        // every wave redundantly reduces the 16 wave maxima (avoids 2nd barrier)
        float v; int i; float x, y, z;
        if (lane < 16) {
            v = redv[pb][lane]; i = redi[pb][lane];
            x = redx[pb][lane]; y = redy[pb][lane]; z = redz[pb][lane];
        } else {
            v = -1.0f; i = 0x7fffffff; x = 0.f; y = 0.f; z = 0.f;
        }
#pragma unroll
        for (int off = 8; off >= 1; off >>= 1) {
            float ov = __shfl_xor(v, off);
            int   oi = __shfl_xor(i, off);
            float ox = __shfl_xor(x, off);
            float oy = __shfl_xor(y, off);
            float oz = __shfl_xor(z, off);
            if (ov > v || (ov == v && oi < i)) { v = ov; i = oi; x = ox; y = oy; z = oz; }
        }
        cx = __shfl(x, 0);
        cy = __shfl(y, 0);
        cz = __shfl(z, 0);
    }
}

// ---------------- Ball query + group: one wave per centroid ----------------
__global__ __launch_bounds__(256) void ballq_kernel(const float* __restrict__ xyz,
                                                    const float* __restrict__ cent,
                                                    float* __restrict__ grouped) {
#pragma clang fp contract(off)
    const int lane = threadIdx.x & 63;
    const int wib = threadIdx.x >> 6;
    const int cid = blockIdx.x * 4 + wib;
    const int b = cid >> 10;
    const float* xb = xyz + (size_t)b * NPTS * 3;
    const float* c = cent + (size_t)cid * 3;
    float cx = c[0], cy = c[1], cz = c[2];
    float* g = grouped + (size_t)cid * NSAMPLE * 3;

    const float R2 = (float)(0.1 * 0.1);

    int total = 0;
    int first_p = -1;

    for (int p0 = 0; p0 < NPTS && total < NSAMPLE; p0 += 64) {
        int p = p0 + lane;
        float x = xb[p * 3 + 0];
        float y = xb[p * 3 + 1];
        float z = xb[p * 3 + 2];
        float dx = x - cx;
        float dy = y - cy;
        float dz = z - cz;
        float d = dx * dx + dy * dy;
        d = d + dz * dz;
        bool hit = d < R2;
        unsigned long long mask = __ballot(hit);
        if (hit) {
            unsigned int mb = __builtin_amdgcn_mbcnt_lo((unsigned int)mask, 0u);
            mb = __builtin_amdgcn_mbcnt_hi((unsigned int)(mask >> 32), mb);
            int pos = total + (int)mb;
            if (pos < NSAMPLE) {
                g[pos * 3 + 0] = dx;
                g[pos * 3 + 1] = dy;
                g[pos * 3 + 2] = dz;
            }
        }
        if (first_p < 0 && mask != 0ull) first_p = p0 + __builtin_ctzll(mask);
        total += __popcll(mask);
    }

    int sel = total < NSAMPLE ? total : NSAMPLE;
    if (sel < NSAMPLE) {
        float fx = xb[first_p * 3 + 0] - cx;
        float fy = xb[first_p * 3 + 1] - cy;
        float fz = xb[first_p * 3 + 2] - cz;
        int s = lane;
        if (s >= sel && s < NSAMPLE) {
            g[s * 3 + 0] = fx;
            g[s * 3 + 1] = fy;
            g[s * 3 + 2] = fz;
        }
    }
}

extern "C" void kernel_launch(void* const* d_in, const int* in_sizes, int n_in,
                              void* d_out, int out_size, void* d_ws, size_t ws_size,
                              hipStream_t stream) {
    const float* xyz = (const float*)d_in[0];
    float* out = (float*)d_out;
    float* grouped = out;
    float* cent = out + (size_t)BATCH * MCENT * NSAMPLE * 3;
    float4* sorted = (float4*)d_ws;  // 16 * 16384 * 16 B = 4 MiB

    sort_kernel<<<BATCH, 1024, 0, stream>>>(xyz, sorted);
    fps_kernel<<<BATCH, 1024, 0, stream>>>(xyz, sorted, cent);
    ballq_kernel<<<(BATCH * MCENT) / 4, 256, 0, stream>>>(xyz, cent, grouped);
}